// Round 6
// baseline (242.911 us; speedup 1.0000x reference)
//
#include <hip/hip_runtime.h>
#include <hip/hip_bf16.h>
#include <hip/hip_fp16.h>
#include <math.h>

#define N_NODES 50000
#define N_EDGES 1600000
#define D_IN    32
#define HID     64
#define HEADS   4
#define D_OUT   32
#define NEG_SLOPE 0.2f
#define NTILES 3125   // N_NODES / 16, exact

// per-octet edge chunks (deg ~ Poisson(32))
#define CQG 64        // gcn_agg
#define CQA 64        // gat_agg (single-pass for ~all nodes; sbuf-only LDS)

// MSD bucket-sort CSR build
#define NBKT 196      // d>>8 buckets (d < 50000)
#define NBLK_A 391    // ceil(1.6M / 4096)
#define TILE_A 4096
#define GH (NBKT * NBLK_A)   // 76636
#define NSB 300       // ceil(GH / 256)
#define CAP 10240     // max bucket size (avg 8163, sigma ~90 -> 23 sigma margin)

typedef _Float16 half8 __attribute__((ext_vector_type(8)));
typedef float    f32x4 __attribute__((ext_vector_type(4)));
typedef float    f32x2 __attribute__((ext_vector_type(2)));

// ---------------------------------------------------------------- CSR: pass A — per-block 196-bin histogram (LDS, per-wave replicas)
__global__ __launch_bounds__(256) void histA(const int* __restrict__ edge,
                                             int* __restrict__ ghist) {
    __shared__ int hist[4][NBKT];
    int t = threadIdx.x, wv = t >> 6;
    for (int i = t; i < 4 * NBKT; i += 256) ((int*)hist)[i] = 0;
    __syncthreads();
    int base = blockIdx.x * TILE_A;
#pragma unroll
    for (int k = 0; k < 16; k++) {
        int i = base + k * 256 + t;
        if (i < N_EDGES) atomicAdd(&hist[wv][edge[N_EDGES + i] >> 8], 1);
    }
    __syncthreads();
    for (int b = t; b < NBKT; b += 256)
        ghist[b * NBLK_A + blockIdx.x] = hist[0][b] + hist[1][b] + hist[2][b] + hist[3][b];
}

// ---------------------------------------------------------------- CSR: pass B — hierarchical coalesced scan of GH entries
__global__ __launch_bounds__(256) void scanB1(const int* __restrict__ g,
                                              int* __restrict__ bsum) {
    int t = threadIdx.x;
    int i = blockIdx.x * 256 + t;
    int v = (i < GH) ? g[i] : 0;              // coalesced
#pragma unroll
    for (int off = 32; off; off >>= 1) v += __shfl_xor(v, off);
    __shared__ int ws[4];
    if ((t & 63) == 0) ws[t >> 6] = v;
    __syncthreads();
    if (t == 0) bsum[blockIdx.x] = ws[0] + ws[1] + ws[2] + ws[3];
}

// block 0: scan of NSB block sums.  block 1: attention projection vectors (fused to save a launch).
__global__ __launch_bounds__(320) void scanB2_attvec(int* __restrict__ bsum,
                                                     const float* __restrict__ W,
                                                     const float* __restrict__ att_s,
                                                     const float* __restrict__ att_d,
                                                     float* __restrict__ vsrc,
                                                     float* __restrict__ vdst) {
    int t = threadIdx.x, lane = t & 63, wv = t >> 6;
    if (blockIdx.x == 0) {
        int v = (t < NSB) ? bsum[t] : 0;
        int inc = v;
#pragma unroll
        for (int d = 1; d < 64; d <<= 1) {
            int u = __shfl_up(inc, d);
            if (lane >= d) inc += u;
        }
        __shared__ int ws[5];
        if (lane == 63) ws[wv] = inc;
        __syncthreads();
        int add = 0;
#pragma unroll
        for (int j = 0; j < 5; j++) if (j < wv) add += ws[j];
        if (t < NSB) bsum[t] = add + inc - v;     // exclusive block offsets
    } else if (t < 256) {
        int h = t >> 6, k = t & 63;
        float s_ = 0.f, d_ = 0.f;
#pragma unroll 8
        for (int c = 0; c < 64; c++) {
            float w = W[k * 256 + h * 64 + c];
            s_ += w * att_s[h * 64 + c];
            d_ += w * att_d[h * 64 + c];
        }
        vsrc[h * 64 + k] = s_;
        vdst[h * 64 + k] = d_;
    }
}

__global__ __launch_bounds__(256) void scanB3(int* __restrict__ g,
                                              const int* __restrict__ bsum) {
    int t = threadIdx.x, lane = t & 63, wv = t >> 6;
    int i = blockIdx.x * 256 + t;
    int v = (i < GH) ? g[i] : 0;              // coalesced
    int inc = v;
#pragma unroll
    for (int d = 1; d < 64; d <<= 1) {
        int u = __shfl_up(inc, d);
        if (lane >= d) inc += u;
    }
    __shared__ int ws[4];
    if (lane == 63) ws[wv] = inc;
    __syncthreads();
    int add = 0;
#pragma unroll
    for (int j = 0; j < 4; j++) if (j < wv) add += ws[j];
    if (i < GH) g[i] = bsum[blockIdx.x] + add + inc - v;   // exclusive prefix
}

// ---------------------------------------------------------------- CSR: pass C — scatter packed (d<<16|s) via LDS cursors (disjoint global ranges)
__global__ __launch_bounds__(256) void scatterC(const int* __restrict__ edge,
                                                const int* __restrict__ ghist,
                                                unsigned* __restrict__ tmp) {
    __shared__ int cur[NBKT];
    int t = threadIdx.x;
    if (t < NBKT) cur[t] = ghist[t * NBLK_A + blockIdx.x];
    __syncthreads();
    int base = blockIdx.x * TILE_A;
#pragma unroll
    for (int k = 0; k < 16; k++) {
        int i = base + k * 256 + t;
        if (i < N_EDGES) {
            int s = edge[i], d = edge[N_EDGES + i];
            int pos = atomicAdd(&cur[d >> 8], 1);     // LDS atomic
            tmp[pos] = ((unsigned)d << 16) | (unsigned)s;
        }
    }
}

// ---------------------------------------------------------------- CSR: pass D — per-bucket 256-bin regroup; emits colidx(u16), rowptr, dinv
__global__ __launch_bounds__(256) void sortD(const unsigned* __restrict__ tmp,
                                             const int* __restrict__ ghist,
                                             unsigned short* __restrict__ colidx,
                                             int* __restrict__ rowptr,
                                             float* __restrict__ dinv) {
    __shared__ unsigned char  dl8[CAP];
    __shared__ unsigned short s16[CAP];
    __shared__ unsigned short o16[CAP];
    __shared__ int hist[4][256];
    __shared__ int excl[256];
    __shared__ int wsum[4];
    int t = threadIdx.x, lane = t & 63, wv = t >> 6;
    int b = blockIdx.x;
    int lo = ghist[b * NBLK_A];
    int hi = (b < NBKT - 1) ? ghist[(b + 1) * NBLK_A] : N_EDGES;
    int size = hi - lo;
    if (size > CAP) size = CAP;           // unreachable safety clamp
    for (int i = t; i < 4 * 256; i += 256) ((int*)hist)[i] = 0;
    __syncthreads();
    for (int i = t; i < size; i += 256) {
        unsigned key = tmp[lo + i];
        int dl = (key >> 16) & 255;
        dl8[i] = (unsigned char)dl;
        s16[i] = (unsigned short)(key & 0xFFFF);
        atomicAdd(&hist[wv][dl], 1);
    }
    __syncthreads();
    int h = hist[0][t] + hist[1][t] + hist[2][t] + hist[3][t];
    int inc = h;
#pragma unroll
    for (int d = 1; d < 64; d <<= 1) {
        int u = __shfl_up(inc, d);
        if (lane >= d) inc += u;
    }
    if (lane == 63) wsum[wv] = inc;
    __syncthreads();
    int add = 0;
#pragma unroll
    for (int j = 0; j < 4; j++) if (j < wv) add += wsum[j];
    int ex = inc - h + add;
    excl[t] = ex;
    int node = b * 256 + t;
    if (node < N_NODES) {
        rowptr[node] = lo + ex;
        dinv[node]   = rsqrtf((float)(h + 1));        // +1 self-loop
    }
    if (b == NBKT - 1 && t == 0) rowptr[N_NODES] = N_EDGES;
    __syncthreads();
    for (int i = t; i < size; i += 256) {
        int pos = atomicAdd(&excl[dl8[i]], 1);        // LDS cursor claim
        o16[pos] = s16[i];
    }
    __syncthreads();
    for (int i = t; i < size; i += 256) colidx[lo + i] = o16[i];
}

// ---------------------------------------------------------------- GEMM1: h = fp16( dinv .* (x @ W_gcn) ); block 0 zeros the pad rows
__global__ __launch_bounds__(256) void gemm1(const float* __restrict__ x,
                                             const float* __restrict__ W,
                                             const float* __restrict__ dinv,
                                             __half* __restrict__ h,
                                             __half* __restrict__ h1) {
    __shared__ float Wl[D_IN * HID];      // 8 KB
    int t = threadIdx.x;
    if (blockIdx.x == 0 && t < HID) {     // zero pad row N_NODES (read by pad lanes in agg kernels)
        h [(size_t)N_NODES * HID + t] = __float2half(0.f);
        h1[(size_t)N_NODES * HID + t] = __float2half(0.f);
    }
    for (int i = t; i < D_IN * HID; i += 256) Wl[i] = W[i];
    __syncthreads();
    int c = t & 63, rw = t >> 6;
    int r0 = blockIdx.x * 32;
#pragma unroll
    for (int rr = 0; rr < 8; rr++) {
        int r = r0 + rr * 4 + rw;
        if (r >= N_NODES) break;
        const float4* xr4 = (const float4*)(x + r * D_IN);
        float acc = 0.f;
#pragma unroll
        for (int k4 = 0; k4 < D_IN / 4; k4++) {
            float4 xv = xr4[k4];
            int k = k4 * 4;
            acc += xv.x * Wl[(k+0)*HID + c] + xv.y * Wl[(k+1)*HID + c]
                 + xv.z * Wl[(k+2)*HID + c] + xv.w * Wl[(k+3)*HID + c];
        }
        h[r * HID + c] = __float2half(acc * dinv[r]);
    }
}

// ---------------------------------------------------------------- GCN aggregate -> h1 fp16 (relu), fused attention dots
// Octet layout (R15, verified): 8 lanes/node, lane holds 8 channels (float4 = 16B gather).
__global__ __launch_bounds__(256) void gcn_agg(const __half* __restrict__ h,
                                               const int* __restrict__ rowptr,
                                               const unsigned short* __restrict__ colidx,
                                               const float* __restrict__ dinv,
                                               const float* __restrict__ b,
                                               const float* __restrict__ vsrc,
                                               const float* __restrict__ vdst,
                                               __half* __restrict__ h1,
                                               float* __restrict__ as_o,
                                               float* __restrict__ ad_o) {
    __shared__ int sbuf[4][8][CQG + 1];   // 8.3 KB
    int lane = threadIdx.x & 63, wv = threadIdx.x >> 6;
    int oct = lane >> 3, ol = lane & 7;
    int n = blockIdx.x * 32 + wv * 8 + oct;
    int nn = min(n, N_NODES - 1);
    int rp = rowptr[nn], re = rowptr[nn + 1];
    int deg = (n < N_NODES) ? (re - rp) : 0;
    int dm = deg;                                  // max degree across the wave's 8 octets
    dm = max(dm, __shfl_xor(dm, 8));
    dm = max(dm, __shfl_xor(dm, 16));
    dm = max(dm, __shfl_xor(dm, 32));
    f32x4 a0 = {0.f,0.f,0.f,0.f}, a1 = {0.f,0.f,0.f,0.f};   // 8 channels
    const __half* hp = h + ol * 8;
    int* sq = sbuf[wv][oct];
    for (int cb = 0; cb < dm; cb += CQG) {
        int m  = min(CQG, max(deg - cb, 0));
        int mm = min(CQG, dm - cb);
        int mm8 = (mm + 7) & ~7;                   // <= CQG
        // stage source offsets: 8-lane stride per octet (all 64 lanes active)
        for (int j = ol; j < m; j += 8)
            sq[j] = (int)colidx[rp + cb + j] * HID;
        for (int j = m + ol; j < mm8; j += 8)
            sq[j] = N_NODES * HID;                 // zero row pad
        // consume: 8 independent 16B gathers in flight (8 rows/instr across octets)
        for (int i0 = 0; i0 < mm8; i0 += 8) {
            float4 raw[8];
#pragma unroll
            for (int k = 0; k < 8; k++)
                raw[k] = *(const float4*)(hp + sq[i0 + k]);   // uniform within octet
#pragma unroll
            for (int k = 0; k < 8; k++) {
                __half2 g0 = __builtin_bit_cast(__half2, raw[k].x);
                __half2 g1 = __builtin_bit_cast(__half2, raw[k].y);
                __half2 g2 = __builtin_bit_cast(__half2, raw[k].z);
                __half2 g3 = __builtin_bit_cast(__half2, raw[k].w);
                float2 f0 = __half22float2(g0), f1 = __half22float2(g1);
                float2 f2 = __half22float2(g2), f3 = __half22float2(g3);
                a0.x += f0.x; a0.y += f0.y; a0.z += f1.x; a0.w += f1.y;
                a1.x += f2.x; a1.y += f2.y; a1.z += f3.x; a1.w += f3.y;
            }
        }
    }
    // self-loop contribution (h pre-scaled by dinv[n])
    {
        float4 raw = *(const float4*)(hp + nn * HID);
        __half2 g0 = __builtin_bit_cast(__half2, raw.x);
        __half2 g1 = __builtin_bit_cast(__half2, raw.y);
        __half2 g2 = __builtin_bit_cast(__half2, raw.z);
        __half2 g3 = __builtin_bit_cast(__half2, raw.w);
        float2 f0 = __half22float2(g0), f1 = __half22float2(g1);
        float2 f2 = __half22float2(g2), f3 = __half22float2(g3);
        a0.x += f0.x; a0.y += f0.y; a0.z += f1.x; a0.w += f1.y;
        a1.x += f2.x; a1.y += f2.y; a1.z += f3.x; a1.w += f3.y;
    }
    float dn = dinv[nn];
    const float4 bb0 = *(const float4*)&b[ol * 8];
    const float4 bb1 = *(const float4*)&b[ol * 8 + 4];
    float v0 = fmaxf(a0.x * dn + bb0.x, 0.f);
    float v1 = fmaxf(a0.y * dn + bb0.y, 0.f);
    float v2 = fmaxf(a0.z * dn + bb0.z, 0.f);
    float v3 = fmaxf(a0.w * dn + bb0.w, 0.f);
    float v4 = fmaxf(a1.x * dn + bb1.x, 0.f);
    float v5 = fmaxf(a1.y * dn + bb1.y, 0.f);
    float v6 = fmaxf(a1.z * dn + bb1.z, 0.f);
    float v7 = fmaxf(a1.w * dn + bb1.w, 0.f);
    if (n < N_NODES) {
        __half2 p0 = __floats2half2_rn(v0, v1);
        __half2 p1 = __floats2half2_rn(v2, v3);
        __half2 p2 = __floats2half2_rn(v4, v5);
        __half2 p3 = __floats2half2_rn(v6, v7);
        float4 pk;
        pk.x = __builtin_bit_cast(float, p0);
        pk.y = __builtin_bit_cast(float, p1);
        pk.z = __builtin_bit_cast(float, p2);
        pk.w = __builtin_bit_cast(float, p3);
        *(float4*)&h1[n * HID + ol * 8] = pk;      // 16B store
    }
    // attention dots: reduce within the 8-lane octet (serves 8 nodes at once)
#pragma unroll
    for (int hh = 0; hh < 4; hh++) {
        const float4 s0 = *(const float4*)&vsrc[hh * 64 + ol * 8];
        const float4 s1 = *(const float4*)&vsrc[hh * 64 + ol * 8 + 4];
        const float4 d0 = *(const float4*)&vdst[hh * 64 + ol * 8];
        const float4 d1 = *(const float4*)&vdst[hh * 64 + ol * 8 + 4];
        float vs = v0*s0.x + v1*s0.y + v2*s0.z + v3*s0.w
                 + v4*s1.x + v5*s1.y + v6*s1.z + v7*s1.w;
        float vd = v0*d0.x + v1*d0.y + v2*d0.z + v3*d0.w
                 + v4*d1.x + v5*d1.y + v6*d1.z + v7*d1.w;
#pragma unroll
        for (int off = 4; off > 0; off >>= 1) {
            vs += __shfl_xor(vs, off);
            vd += __shfl_xor(vd, off);
        }
        if (ol == 0 && n < N_NODES) {
            as_o[n * 4 + hh] = vs;
            ad_o[n * 4 + hh] = vd;
        }
    }
}

// ---------------------------------------------------------------- GAT aggregate (no max pass; self-loop analytic) -> u fp16
// R16: SINGLE-PHASE octet layout. Stage only colidx (s) to LDS; in the consume burst each
// octet loads a_s[s*4] (16B octet-uniform) AND h1[s*64] (16B/lane) as two independent
// gather streams, computes leaky+exp weights IN-REGISTER (octet-redundant, octet-uniform).
// Removes: phase-B dependent-gather chain, wbuf LDS (21KB -> 8.4KB), denominator reduce.
__global__ __launch_bounds__(256) void gat_agg(const __half* __restrict__ h1,
                                               const int* __restrict__ rowptr,
                                               const unsigned short* __restrict__ colidx,
                                               const float* __restrict__ a_s,
                                               const float* __restrict__ a_d,
                                               __half* __restrict__ u) {
    __shared__ int sbuf[4][8][CQA + 1];   // 8.4 KB
    int lane = threadIdx.x & 63, wv = threadIdx.x >> 6;
    int oct = lane >> 3, ol = lane & 7;
    int n = blockIdx.x * 32 + wv * 8 + oct;
    int nn = min(n, N_NODES - 1);
    int rp = rowptr[nn], re = rowptr[nn + 1];
    int deg = (n < N_NODES) ? (re - rp) : 0;
    int dm = deg;
    dm = max(dm, __shfl_xor(dm, 8));
    dm = max(dm, __shfl_xor(dm, 16));
    dm = max(dm, __shfl_xor(dm, 32));
    float4 ad4 = *(const float4*)&a_d[nn * 4];

    float dnx = 0.f, dny = 0.f, dnz = 0.f, dnw = 0.f;
    f32x4 accA[4], accB[4];                  // [head][ch 0-3], [head][ch 4-7]
#pragma unroll
    for (int hh = 0; hh < 4; hh++) { accA[hh] = (f32x4){0.f,0.f,0.f,0.f}; accB[hh] = (f32x4){0.f,0.f,0.f,0.f}; }
    const __half* hp = h1 + ol * 8;
    int* sq = sbuf[wv][oct];
    for (int cb = 0; cb < dm; cb += CQA) {
        int m  = min(CQA, max(deg - cb, 0));
        int mm = min(CQA, dm - cb);
        int mm4 = (mm + 3) & ~3;                   // <= CQA
        // stage raw source node ids (coalesced 16B/octet colidx reads)
        for (int j = ol; j < m; j += 8)
            sq[j] = (int)colidx[rp + cb + j];
        for (int j = m + ol; j < mm4; j += 8)
            sq[j] = N_NODES;                       // sentinel: zero h1 row, w forced 0
        // consume: per 4-edge burst, 8 independent loads (4x a_s + 4x h1) in flight
        for (int i0 = 0; i0 < mm4; i0 += 4) {
            int    sk[4];
            float4 aw[4];
            float4 raw[4];
#pragma unroll
            for (int k = 0; k < 4; k++) {
                int s = sq[i0 + k];                // LDS broadcast within octet
                sk[k] = s;
                int sa = min(s, N_NODES - 1);
                aw[k]  = *(const float4*)&a_s[sa * 4];          // octet-uniform 16B
                raw[k] = *(const float4*)(hp + s * HID);        // 16B/lane gather
            }
#pragma unroll
            for (int k = 0; k < 4; k++) {
                float4 a = aw[k];
                float vx = a.x + ad4.x; vx = fmaxf(vx, NEG_SLOPE * vx);
                float vy = a.y + ad4.y; vy = fmaxf(vy, NEG_SLOPE * vy);
                float vz = a.z + ad4.z; vz = fmaxf(vz, NEG_SLOPE * vz);
                float vw = a.w + ad4.w; vw = fmaxf(vw, NEG_SLOPE * vw);
                bool val = sk[k] < N_NODES;
                float wx = val ? __expf(vx) : 0.f;
                float wy = val ? __expf(vy) : 0.f;
                float wz = val ? __expf(vz) : 0.f;
                float ww = val ? __expf(vw) : 0.f;
                dnx += wx; dny += wy; dnz += wz; dnw += ww;
                __half2 g0 = __builtin_bit_cast(__half2, raw[k].x);
                __half2 g1 = __builtin_bit_cast(__half2, raw[k].y);
                __half2 g2 = __builtin_bit_cast(__half2, raw[k].z);
                __half2 g3 = __builtin_bit_cast(__half2, raw[k].w);
                float2 f0 = __half22float2(g0), f1 = __half22float2(g1);
                float2 f2 = __half22float2(g2), f3 = __half22float2(g3);
                f32x4 flo = {f0.x, f0.y, f1.x, f1.y};
                f32x4 fhi = {f2.x, f2.y, f3.x, f3.y};
                f32x4 wxv = {wx, wx, wx, wx};
                f32x4 wyv = {wy, wy, wy, wy};
                f32x4 wzv = {wz, wz, wz, wz};
                f32x4 wwv = {ww, ww, ww, ww};
                accA[0] += wxv * flo; accB[0] += wxv * fhi;
                accA[1] += wyv * flo; accB[1] += wyv * fhi;
                accA[2] += wzv * flo; accB[2] += wzv * fhi;
                accA[3] += wwv * flo; accB[3] += wwv * fhi;
            }
        }
    }
    // NOTE: no denominator reduce — every lane of the octet accumulated every edge.
    // self-loop: w_self per head (uniform within octet)
    float4 asn = *(const float4*)&a_s[nn * 4];
    float sx = asn.x + ad4.x; sx = fmaxf(sx, NEG_SLOPE * sx);
    float sy = asn.y + ad4.y; sy = fmaxf(sy, NEG_SLOPE * sy);
    float sz = asn.z + ad4.z; sz = fmaxf(sz, NEG_SLOPE * sz);
    float sw = asn.w + ad4.w; sw = fmaxf(sw, NEG_SLOPE * sw);
    float wsx = __expf(sx), wsy = __expf(sy);
    float wsz = __expf(sz), wsw = __expf(sw);
    dnx += wsx; dny += wsy; dnz += wsz; dnw += wsw;
    {
        float4 raw = *(const float4*)(hp + nn * HID);
        __half2 g0 = __builtin_bit_cast(__half2, raw.x);
        __half2 g1 = __builtin_bit_cast(__half2, raw.y);
        __half2 g2 = __builtin_bit_cast(__half2, raw.z);
        __half2 g3 = __builtin_bit_cast(__half2, raw.w);
        float2 f0 = __half22float2(g0), f1 = __half22float2(g1);
        float2 f2 = __half22float2(g2), f3 = __half22float2(g3);
        f32x4 flo = {f0.x, f0.y, f1.x, f1.y};
        f32x4 fhi = {f2.x, f2.y, f3.x, f3.y};
        accA[0] += (f32x4){wsx,wsx,wsx,wsx} * flo; accB[0] += (f32x4){wsx,wsx,wsx,wsx} * fhi;
        accA[1] += (f32x4){wsy,wsy,wsy,wsy} * flo; accB[1] += (f32x4){wsy,wsy,wsy,wsy} * fhi;
        accA[2] += (f32x4){wsz,wsz,wsz,wsz} * flo; accB[2] += (f32x4){wsz,wsz,wsz,wsz} * fhi;
        accA[3] += (f32x4){wsw,wsw,wsw,wsw} * flo; accB[3] += (f32x4){wsw,wsw,wsw,wsw} * fhi;
    }
    if (n < N_NODES) {
        float r4[4] = {1.f / dnx, 1.f / dny, 1.f / dnz, 1.f / dnw};
        __half* up = u + (size_t)n * 256 + ol * 8;
#pragma unroll
        for (int hh = 0; hh < 4; hh++) {
            float r = r4[hh];
            __half2 p0 = __floats2half2_rn(accA[hh].x * r, accA[hh].y * r);
            __half2 p1 = __floats2half2_rn(accA[hh].z * r, accA[hh].w * r);
            __half2 p2 = __floats2half2_rn(accB[hh].x * r, accB[hh].y * r);
            __half2 p3 = __floats2half2_rn(accB[hh].z * r, accB[hh].w * r);
            float4 pk;
            pk.x = __builtin_bit_cast(float, p0);
            pk.y = __builtin_bit_cast(float, p1);
            pk.z = __builtin_bit_cast(float, p2);
            pk.w = __builtin_bit_cast(float, p3);
            *(float4*)&up[hh * 64] = pk;           // 16B store per head
        }
    }
}

// ---------------------------------------------------------------- gemm2b (MFMA): h2 = fp16 relu(u @ blockdiag(W_gat) + b)
__global__ __launch_bounds__(256) void gemm2b(const __half* __restrict__ u,
                                              const float* __restrict__ W,
                                              const float* __restrict__ b,
                                              __half* __restrict__ h2) {
    int lane = threadIdx.x & 63, hd = threadIdx.x >> 6;
    int quad = lane >> 4, l16 = lane & 15;
    half8 Bf[4][2];
#pragma unroll
    for (int nt = 0; nt < 4; nt++)
#pragma unroll
        for (int kc = 0; kc < 2; kc++) {
            const float* wp = W + (kc * 32 + quad * 8) * 256 + hd * 64 + nt * 16 + l16;
#pragma unroll
            for (int j = 0; j < 8; j++)
                Bf[nt][kc][j] = (_Float16)wp[j * 256];
        }
    float bb[4];
#pragma unroll
    for (int nt = 0; nt < 4; nt++) bb[nt] = b[hd * 64 + nt * 16 + l16];

    int rt0 = blockIdx.x * 5;
#pragma unroll
    for (int i = 0; i < 5; i++) {
        int rt = rt0 + i;
        const __half* up = u + ((size_t)(rt * 16 + l16)) * 256 + hd * 64 + quad * 8;
        half8 A0 = *(const half8*)(const void*)up;
        half8 A1 = *(const half8*)(const void*)(up + 32);
        f32x4 acc[4];
#pragma unroll
        for (int nt = 0; nt < 4; nt++) {
            acc[nt] = (f32x4){0.f, 0.f, 0.f, 0.f};
            acc[nt] = __builtin_amdgcn_mfma_f32_16x16x32_f16(A0, Bf[nt][0], acc[nt], 0, 0, 0);
            acc[nt] = __builtin_amdgcn_mfma_f32_16x16x32_f16(A1, Bf[nt][1], acc[nt], 0, 0, 0);
        }
#pragma unroll
        for (int nt = 0; nt < 4; nt++) {
            int col = hd * 64 + nt * 16 + l16;
#pragma unroll
            for (int reg = 0; reg < 4; reg++) {
                int row = rt * 16 + quad * 4 + reg;
                h2[(size_t)row * 256 + col] = __float2half(fmaxf(acc[nt][reg] + bb[nt], 0.f));
            }
        }
    }
}

// ---------------------------------------------------------------- gemm3 (MFMA): out = h2 @ W_fc + b_fc
__global__ __launch_bounds__(256) void gemm3(const __half* __restrict__ h2,
                                             const float* __restrict__ W,
                                             const float* __restrict__ b,
                                             float* __restrict__ out) {
    int lane = threadIdx.x & 63, wv = threadIdx.x >> 6;
    int quad = lane >> 4, l16 = lane & 15;
    half8 Bf[2][8];
#pragma unroll
    for (int nt = 0; nt < 2; nt++)
#pragma unroll
        for (int kc = 0; kc < 8; kc++) {
            const float* wp = W + (kc * 32 + quad * 8) * 32 + nt * 16 + l16;
#pragma unroll
            for (int j = 0; j < 8; j++)
                Bf[nt][kc][j] = (_Float16)wp[j * 32];
        }
    float bb0 = b[l16], bb1 = b[16 + l16];

    for (int tile = blockIdx.x * 4 + wv; tile < NTILES; tile += gridDim.x * 4) {
        const __half* hp = h2 + (size_t)(tile * 16 + l16) * 256 + quad * 8;
        f32x4 acc0 = {0.f, 0.f, 0.f, 0.f};
        f32x4 acc1 = {0.f, 0.f, 0.f, 0.f};
#pragma unroll
        for (int kc = 0; kc < 8; kc++) {
            half8 A = *(const half8*)(const void*)(hp + kc * 32);
            acc0 = __builtin_amdgcn_mfma_f32_16x16x32_f16(A, Bf[0][kc], acc0, 0, 0, 0);
            acc1 = __builtin_amdgcn_mfma_f32_16x16x32_f16(A, Bf[1][kc], acc1, 0, 0, 0);
        }
#pragma unroll
        for (int reg = 0; reg < 4; reg++) {
            int row = tile * 16 + quad * 4 + reg;
            out[row * 32 + l16]      = acc0[reg] + bb0;
            out[row * 32 + 16 + l16] = acc1[reg] + bb1;
        }
    }
}

// ---------------------------------------------------------------- launch
extern "C" void kernel_launch(void* const* d_in, const int* in_sizes, int n_in,
                              void* d_out, int out_size, void* d_ws, size_t ws_size,
                              hipStream_t stream) {
    const float* x      = (const float*)d_in[0];
    const int*   edge   = (const int*)  d_in[1];
    const float* W_gcn  = (const float*)d_in[2];
    const float* b_gcn  = (const float*)d_in[3];
    const float* W_gat  = (const float*)d_in[4];
    const float* att_s  = (const float*)d_in[5];
    const float* att_d  = (const float*)d_in[6];
    const float* b_gat  = (const float*)d_in[7];
    const float* W_fc   = (const float*)d_in[8];
    const float* b_fc   = (const float*)d_in[9];
    float* out = (float*)d_out;

    char* p = (char*)d_ws;
    auto alloc = [&](size_t bytes) {
        char* q = p;
        p += (bytes + 255) & ~(size_t)255;
        return q;
    };
    __half* h     = (__half*)alloc((size_t)(N_NODES + 1) * HID * 2);   // +1 zero row
    __half* h1    = (__half*)alloc((size_t)(N_NODES + 1) * HID * 2);   // +1 zero row
    __half* u     = (__half*)alloc((size_t)N_NODES * 256 * 2);
    __half* h2    = (__half*)alloc((size_t)N_NODES * 256 * 2);
    float* as_a   = (float*)alloc((size_t)N_NODES * 4 * 4);
    float* ad_a   = (float*)alloc((size_t)N_NODES * 4 * 4);
    float* dinv   = (float*)alloc((size_t)N_NODES * 4);
    int*   rowptr = (int*)  alloc((size_t)(N_NODES + 1) * 4);
    unsigned short* colidx = (unsigned short*)alloc((size_t)N_EDGES * 2);
    int*   ghist  = (int*)  alloc((size_t)GH * 4);
    int*   bsum   = (int*)  alloc((size_t)NSB * 4);
    unsigned* tmp = (unsigned*)alloc((size_t)N_EDGES * 4);
    float* vsrc   = (float*)alloc((size_t)HEADS * HID * 4);
    float* vdst   = (float*)alloc((size_t)HEADS * HID * 4);

    // CSR build: atomic-free MSD bucket sort (hierarchical coalesced scan; attvec fused into scanB2)
    histA        <<<NBLK_A, 256, 0, stream>>>(edge, ghist);
    scanB1       <<<NSB, 256, 0, stream>>>(ghist, bsum);
    scanB2_attvec<<<2, 320, 0, stream>>>(bsum, W_gat, att_s, att_d, vsrc, vdst);
    scanB3       <<<NSB, 256, 0, stream>>>(ghist, bsum);
    scatterC     <<<NBLK_A, 256, 0, stream>>>(edge, ghist, tmp);
    sortD        <<<NBKT, 256, 0, stream>>>(tmp, ghist, colidx, rowptr, dinv);

    // GCN (gemm1 also zeroes the pad rows of h/h1)
    gemm1   <<<(N_NODES + 31) / 32, 256, 0, stream>>>(x, W_gcn, dinv, h, h1);
    gcn_agg <<<(N_NODES + 31) / 32, 256, 0, stream>>>(h, rowptr, colidx, dinv, b_gcn,
                                                      vsrc, vdst, h1, as_a, ad_a);

    // GAT
    gat_agg <<<(N_NODES + 31) / 32, 256, 0, stream>>>(h1, rowptr, colidx, as_a, ad_a, u);
    gemm2b  <<<625, 256, 0, stream>>>(u, W_gat, b_gat, h2);

    // FC
    gemm3   <<<256, 256, 0, stream>>>(h2, W_fc, b_fc, out);
}

// Round 7
// 214.520 us; speedup vs baseline: 1.1323x; 1.1323x over previous
//
#include <hip/hip_runtime.h>
#include <hip/hip_bf16.h>
#include <hip/hip_fp16.h>
#include <math.h>

#define N_NODES 50000
#define N_EDGES 1600000
#define D_IN    32
#define HID     64
#define HEADS   4
#define D_OUT   32
#define NEG_SLOPE 0.2f
#define NTILES 3125   // N_NODES / 16, exact

// per-octet edge chunks (deg ~ Poisson(32))
#define CQG 64        // gcn_agg
#define CQA 32        // gat_agg (wbuf LDS budget) — R5 verified two-phase structure

// MSD bucket-sort CSR build
#define NBKT 196      // d>>8 buckets (d < 50000)
#define NBLK_A 391    // ceil(1.6M / 4096)
#define TILE_A 4096
#define GH (NBKT * NBLK_A)   // 76636
#define NSB 300       // ceil(GH / 256)
#define CAP 10240     // max bucket size (avg 8163, sigma ~90 -> 23 sigma margin)

typedef _Float16 half8 __attribute__((ext_vector_type(8)));
typedef float    f32x4 __attribute__((ext_vector_type(4)));
typedef float    f32x2 __attribute__((ext_vector_type(2)));

// ---------------------------------------------------------------- CSR: pass A — per-block 196-bin histogram (LDS, per-wave replicas)
__global__ __launch_bounds__(256) void histA(const int* __restrict__ edge,
                                             int* __restrict__ ghist) {
    __shared__ int hist[4][NBKT];
    int t = threadIdx.x, wv = t >> 6;
    for (int i = t; i < 4 * NBKT; i += 256) ((int*)hist)[i] = 0;
    __syncthreads();
    int base = blockIdx.x * TILE_A;
#pragma unroll
    for (int k = 0; k < 16; k++) {
        int i = base + k * 256 + t;
        if (i < N_EDGES) atomicAdd(&hist[wv][edge[N_EDGES + i] >> 8], 1);
    }
    __syncthreads();
    for (int b = t; b < NBKT; b += 256)
        ghist[b * NBLK_A + blockIdx.x] = hist[0][b] + hist[1][b] + hist[2][b] + hist[3][b];
}

// ---------------------------------------------------------------- CSR: pass B — hierarchical coalesced scan of GH entries
__global__ __launch_bounds__(256) void scanB1(const int* __restrict__ g,
                                              int* __restrict__ bsum) {
    int t = threadIdx.x;
    int i = blockIdx.x * 256 + t;
    int v = (i < GH) ? g[i] : 0;              // coalesced
#pragma unroll
    for (int off = 32; off; off >>= 1) v += __shfl_xor(v, off);
    __shared__ int ws[4];
    if ((t & 63) == 0) ws[t >> 6] = v;
    __syncthreads();
    if (t == 0) bsum[blockIdx.x] = ws[0] + ws[1] + ws[2] + ws[3];
}

// block 0: scan of NSB block sums.  block 1: attention projection vectors (fused to save a launch).
__global__ __launch_bounds__(320) void scanB2_attvec(int* __restrict__ bsum,
                                                     const float* __restrict__ W,
                                                     const float* __restrict__ att_s,
                                                     const float* __restrict__ att_d,
                                                     float* __restrict__ vsrc,
                                                     float* __restrict__ vdst) {
    int t = threadIdx.x, lane = t & 63, wv = t >> 6;
    if (blockIdx.x == 0) {
        int v = (t < NSB) ? bsum[t] : 0;
        int inc = v;
#pragma unroll
        for (int d = 1; d < 64; d <<= 1) {
            int u = __shfl_up(inc, d);
            if (lane >= d) inc += u;
        }
        __shared__ int ws[5];
        if (lane == 63) ws[wv] = inc;
        __syncthreads();
        int add = 0;
#pragma unroll
        for (int j = 0; j < 5; j++) if (j < wv) add += ws[j];
        if (t < NSB) bsum[t] = add + inc - v;     // exclusive block offsets
    } else if (t < 256) {
        int h = t >> 6, k = t & 63;
        float s_ = 0.f, d_ = 0.f;
#pragma unroll 8
        for (int c = 0; c < 64; c++) {
            float w = W[k * 256 + h * 64 + c];
            s_ += w * att_s[h * 64 + c];
            d_ += w * att_d[h * 64 + c];
        }
        vsrc[h * 64 + k] = s_;
        vdst[h * 64 + k] = d_;
    }
}

__global__ __launch_bounds__(256) void scanB3(int* __restrict__ g,
                                              const int* __restrict__ bsum) {
    int t = threadIdx.x, lane = t & 63, wv = t >> 6;
    int i = blockIdx.x * 256 + t;
    int v = (i < GH) ? g[i] : 0;              // coalesced
    int inc = v;
#pragma unroll
    for (int d = 1; d < 64; d <<= 1) {
        int u = __shfl_up(inc, d);
        if (lane >= d) inc += u;
    }
    __shared__ int ws[4];
    if (lane == 63) ws[wv] = inc;
    __syncthreads();
    int add = 0;
#pragma unroll
    for (int j = 0; j < 4; j++) if (j < wv) add += ws[j];
    if (i < GH) g[i] = bsum[blockIdx.x] + add + inc - v;   // exclusive prefix
}

// ---------------------------------------------------------------- CSR: pass C — scatter packed (d<<16|s) via LDS cursors (disjoint global ranges)
__global__ __launch_bounds__(256) void scatterC(const int* __restrict__ edge,
                                                const int* __restrict__ ghist,
                                                unsigned* __restrict__ tmp) {
    __shared__ int cur[NBKT];
    int t = threadIdx.x;
    if (t < NBKT) cur[t] = ghist[t * NBLK_A + blockIdx.x];
    __syncthreads();
    int base = blockIdx.x * TILE_A;
#pragma unroll
    for (int k = 0; k < 16; k++) {
        int i = base + k * 256 + t;
        if (i < N_EDGES) {
            int s = edge[i], d = edge[N_EDGES + i];
            int pos = atomicAdd(&cur[d >> 8], 1);     // LDS atomic
            tmp[pos] = ((unsigned)d << 16) | (unsigned)s;
        }
    }
}

// ---------------------------------------------------------------- CSR: pass D — per-bucket 256-bin regroup; emits colidx(u16), rowptr, dinv
__global__ __launch_bounds__(256) void sortD(const unsigned* __restrict__ tmp,
                                             const int* __restrict__ ghist,
                                             unsigned short* __restrict__ colidx,
                                             int* __restrict__ rowptr,
                                             float* __restrict__ dinv) {
    __shared__ unsigned char  dl8[CAP];
    __shared__ unsigned short s16[CAP];
    __shared__ unsigned short o16[CAP];
    __shared__ int hist[4][256];
    __shared__ int excl[256];
    __shared__ int wsum[4];
    int t = threadIdx.x, lane = t & 63, wv = t >> 6;
    int b = blockIdx.x;
    int lo = ghist[b * NBLK_A];
    int hi = (b < NBKT - 1) ? ghist[(b + 1) * NBLK_A] : N_EDGES;
    int size = hi - lo;
    if (size > CAP) size = CAP;           // unreachable safety clamp
    for (int i = t; i < 4 * 256; i += 256) ((int*)hist)[i] = 0;
    __syncthreads();
    for (int i = t; i < size; i += 256) {
        unsigned key = tmp[lo + i];
        int dl = (key >> 16) & 255;
        dl8[i] = (unsigned char)dl;
        s16[i] = (unsigned short)(key & 0xFFFF);
        atomicAdd(&hist[wv][dl], 1);
    }
    __syncthreads();
    int h = hist[0][t] + hist[1][t] + hist[2][t] + hist[3][t];
    int inc = h;
#pragma unroll
    for (int d = 1; d < 64; d <<= 1) {
        int u = __shfl_up(inc, d);
        if (lane >= d) inc += u;
    }
    if (lane == 63) wsum[wv] = inc;
    __syncthreads();
    int add = 0;
#pragma unroll
    for (int j = 0; j < 4; j++) if (j < wv) add += wsum[j];
    int ex = inc - h + add;
    excl[t] = ex;
    int node = b * 256 + t;
    if (node < N_NODES) {
        rowptr[node] = lo + ex;
        dinv[node]   = rsqrtf((float)(h + 1));        // +1 self-loop
    }
    if (b == NBKT - 1 && t == 0) rowptr[N_NODES] = N_EDGES;
    __syncthreads();
    for (int i = t; i < size; i += 256) {
        int pos = atomicAdd(&excl[dl8[i]], 1);        // LDS cursor claim
        o16[pos] = s16[i];
    }
    __syncthreads();
    for (int i = t; i < size; i += 256) colidx[lo + i] = o16[i];
}

// ---------------------------------------------------------------- GEMM1: h = fp16( dinv .* (x @ W_gcn) ); block 0 zeros the pad rows
__global__ __launch_bounds__(256) void gemm1(const float* __restrict__ x,
                                             const float* __restrict__ W,
                                             const float* __restrict__ dinv,
                                             __half* __restrict__ h,
                                             __half* __restrict__ h1) {
    __shared__ float Wl[D_IN * HID];      // 8 KB
    int t = threadIdx.x;
    if (blockIdx.x == 0 && t < HID) {     // zero pad row N_NODES (read by pad lanes in agg kernels)
        h [(size_t)N_NODES * HID + t] = __float2half(0.f);
        h1[(size_t)N_NODES * HID + t] = __float2half(0.f);
    }
    for (int i = t; i < D_IN * HID; i += 256) Wl[i] = W[i];
    __syncthreads();
    int c = t & 63, rw = t >> 6;
    int r0 = blockIdx.x * 32;
#pragma unroll
    for (int rr = 0; rr < 8; rr++) {
        int r = r0 + rr * 4 + rw;
        if (r >= N_NODES) break;
        const float4* xr4 = (const float4*)(x + r * D_IN);
        float acc = 0.f;
#pragma unroll
        for (int k4 = 0; k4 < D_IN / 4; k4++) {
            float4 xv = xr4[k4];
            int k = k4 * 4;
            acc += xv.x * Wl[(k+0)*HID + c] + xv.y * Wl[(k+1)*HID + c]
                 + xv.z * Wl[(k+2)*HID + c] + xv.w * Wl[(k+3)*HID + c];
        }
        h[r * HID + c] = __float2half(acc * dinv[r]);
    }
}

// ---------------------------------------------------------------- GCN aggregate -> h1 fp16 (relu), fused attention dots
// Octet layout (R15, verified): 8 lanes/node, lane holds 8 channels (float4 = 16B gather).
__global__ __launch_bounds__(256) void gcn_agg(const __half* __restrict__ h,
                                               const int* __restrict__ rowptr,
                                               const unsigned short* __restrict__ colidx,
                                               const float* __restrict__ dinv,
                                               const float* __restrict__ b,
                                               const float* __restrict__ vsrc,
                                               const float* __restrict__ vdst,
                                               __half* __restrict__ h1,
                                               float* __restrict__ as_o,
                                               float* __restrict__ ad_o) {
    __shared__ int sbuf[4][8][CQG + 1];   // 8.3 KB
    int lane = threadIdx.x & 63, wv = threadIdx.x >> 6;
    int oct = lane >> 3, ol = lane & 7;
    int n = blockIdx.x * 32 + wv * 8 + oct;
    int nn = min(n, N_NODES - 1);
    int rp = rowptr[nn], re = rowptr[nn + 1];
    int deg = (n < N_NODES) ? (re - rp) : 0;
    int dm = deg;                                  // max degree across the wave's 8 octets
    dm = max(dm, __shfl_xor(dm, 8));
    dm = max(dm, __shfl_xor(dm, 16));
    dm = max(dm, __shfl_xor(dm, 32));
    f32x4 a0 = {0.f,0.f,0.f,0.f}, a1 = {0.f,0.f,0.f,0.f};   // 8 channels
    const __half* hp = h + ol * 8;
    int* sq = sbuf[wv][oct];
    for (int cb = 0; cb < dm; cb += CQG) {
        int m  = min(CQG, max(deg - cb, 0));
        int mm = min(CQG, dm - cb);
        int mm8 = (mm + 7) & ~7;                   // <= CQG
        // stage source offsets: 8-lane stride per octet (all 64 lanes active)
        for (int j = ol; j < m; j += 8)
            sq[j] = (int)colidx[rp + cb + j] * HID;
        for (int j = m + ol; j < mm8; j += 8)
            sq[j] = N_NODES * HID;                 // zero row pad
        // consume: 8 independent 16B gathers in flight (8 rows/instr across octets)
        for (int i0 = 0; i0 < mm8; i0 += 8) {
            float4 raw[8];
#pragma unroll
            for (int k = 0; k < 8; k++)
                raw[k] = *(const float4*)(hp + sq[i0 + k]);   // uniform within octet
#pragma unroll
            for (int k = 0; k < 8; k++) {
                __half2 g0 = __builtin_bit_cast(__half2, raw[k].x);
                __half2 g1 = __builtin_bit_cast(__half2, raw[k].y);
                __half2 g2 = __builtin_bit_cast(__half2, raw[k].z);
                __half2 g3 = __builtin_bit_cast(__half2, raw[k].w);
                float2 f0 = __half22float2(g0), f1 = __half22float2(g1);
                float2 f2 = __half22float2(g2), f3 = __half22float2(g3);
                a0.x += f0.x; a0.y += f0.y; a0.z += f1.x; a0.w += f1.y;
                a1.x += f2.x; a1.y += f2.y; a1.z += f3.x; a1.w += f3.y;
            }
        }
    }
    // self-loop contribution (h pre-scaled by dinv[n])
    {
        float4 raw = *(const float4*)(hp + nn * HID);
        __half2 g0 = __builtin_bit_cast(__half2, raw.x);
        __half2 g1 = __builtin_bit_cast(__half2, raw.y);
        __half2 g2 = __builtin_bit_cast(__half2, raw.z);
        __half2 g3 = __builtin_bit_cast(__half2, raw.w);
        float2 f0 = __half22float2(g0), f1 = __half22float2(g1);
        float2 f2 = __half22float2(g2), f3 = __half22float2(g3);
        a0.x += f0.x; a0.y += f0.y; a0.z += f1.x; a0.w += f1.y;
        a1.x += f2.x; a1.y += f2.y; a1.z += f3.x; a1.w += f3.y;
    }
    float dn = dinv[nn];
    const float4 bb0 = *(const float4*)&b[ol * 8];
    const float4 bb1 = *(const float4*)&b[ol * 8 + 4];
    float v0 = fmaxf(a0.x * dn + bb0.x, 0.f);
    float v1 = fmaxf(a0.y * dn + bb0.y, 0.f);
    float v2 = fmaxf(a0.z * dn + bb0.z, 0.f);
    float v3 = fmaxf(a0.w * dn + bb0.w, 0.f);
    float v4 = fmaxf(a1.x * dn + bb1.x, 0.f);
    float v5 = fmaxf(a1.y * dn + bb1.y, 0.f);
    float v6 = fmaxf(a1.z * dn + bb1.z, 0.f);
    float v7 = fmaxf(a1.w * dn + bb1.w, 0.f);
    if (n < N_NODES) {
        __half2 p0 = __floats2half2_rn(v0, v1);
        __half2 p1 = __floats2half2_rn(v2, v3);
        __half2 p2 = __floats2half2_rn(v4, v5);
        __half2 p3 = __floats2half2_rn(v6, v7);
        float4 pk;
        pk.x = __builtin_bit_cast(float, p0);
        pk.y = __builtin_bit_cast(float, p1);
        pk.z = __builtin_bit_cast(float, p2);
        pk.w = __builtin_bit_cast(float, p3);
        *(float4*)&h1[n * HID + ol * 8] = pk;      // 16B store
    }
    // attention dots: reduce within the 8-lane octet (serves 8 nodes at once)
#pragma unroll
    for (int hh = 0; hh < 4; hh++) {
        const float4 s0 = *(const float4*)&vsrc[hh * 64 + ol * 8];
        const float4 s1 = *(const float4*)&vsrc[hh * 64 + ol * 8 + 4];
        const float4 d0 = *(const float4*)&vdst[hh * 64 + ol * 8];
        const float4 d1 = *(const float4*)&vdst[hh * 64 + ol * 8 + 4];
        float vs = v0*s0.x + v1*s0.y + v2*s0.z + v3*s0.w
                 + v4*s1.x + v5*s1.y + v6*s1.z + v7*s1.w;
        float vd = v0*d0.x + v1*d0.y + v2*d0.z + v3*d0.w
                 + v4*d1.x + v5*d1.y + v6*d1.z + v7*d1.w;
#pragma unroll
        for (int off = 4; off > 0; off >>= 1) {
            vs += __shfl_xor(vs, off);
            vd += __shfl_xor(vd, off);
        }
        if (ol == 0 && n < N_NODES) {
            as_o[n * 4 + hh] = vs;
            ad_o[n * 4 + hh] = vd;
        }
    }
}

// ---------------------------------------------------------------- GAT aggregate (no max pass; self-loop analytic) -> u fp16
// R5-verified two-phase octet layout: 8 lanes/node, lane holds 8 channels; 1KB gathered
// per wave instr. Weight phase at 8-lane stride; denominators reduced over 8 lanes.
__global__ __launch_bounds__(256) void gat_agg(const __half* __restrict__ h1,
                                               const int* __restrict__ rowptr,
                                               const unsigned short* __restrict__ colidx,
                                               const float* __restrict__ a_s,
                                               const float* __restrict__ a_d,
                                               __half* __restrict__ u) {
    __shared__ float4 wbuf[4][8][CQA + 1];   // 16.9 KB
    __shared__ int    sbuf[4][8][CQA + 1];   //  4.2 KB
    int lane = threadIdx.x & 63, wv = threadIdx.x >> 6;
    int oct = lane >> 3, ol = lane & 7;
    int n = blockIdx.x * 32 + wv * 8 + oct;
    int nn = min(n, N_NODES - 1);
    int rp = rowptr[nn], re = rowptr[nn + 1];
    int deg = (n < N_NODES) ? (re - rp) : 0;
    int dm = deg;
    dm = max(dm, __shfl_xor(dm, 8));
    dm = max(dm, __shfl_xor(dm, 16));
    dm = max(dm, __shfl_xor(dm, 32));
    float4 ad4 = *(const float4*)&a_d[nn * 4];

    float dnx = 0.f, dny = 0.f, dnz = 0.f, dnw = 0.f;
    f32x4 accA[4], accB[4];                  // [head][ch 0-3], [head][ch 4-7]
#pragma unroll
    for (int hh = 0; hh < 4; hh++) { accA[hh] = (f32x4){0.f,0.f,0.f,0.f}; accB[hh] = (f32x4){0.f,0.f,0.f,0.f}; }
    const __half* hp = h1 + ol * 8;
    int*    sq = sbuf[wv][oct];
    float4* wq = wbuf[wv][oct];
    for (int cb = 0; cb < dm; cb += CQA) {
        int m  = min(CQA, max(deg - cb, 0));
        int mm = min(CQA, dm - cb);
        int mm8 = (mm + 7) & ~7;                   // <= CQA
        // phase B: weights at 8-lane stride per octet (no clamp: logits are O(+-6), fp32 exp safe)
        for (int j = ol; j < m; j += 8) {
            int s = colidx[rp + cb + j];
            float4 a = *(const float4*)&a_s[s * 4];
            float vx = a.x + ad4.x; vx = fmaxf(vx, NEG_SLOPE * vx);
            float vy = a.y + ad4.y; vy = fmaxf(vy, NEG_SLOPE * vy);
            float vz = a.z + ad4.z; vz = fmaxf(vz, NEG_SLOPE * vz);
            float vw = a.w + ad4.w; vw = fmaxf(vw, NEG_SLOPE * vw);
            float wx = __expf(vx), wy = __expf(vy);
            float wz = __expf(vz), ww = __expf(vw);
            dnx += wx; dny += wy; dnz += wz; dnw += ww;
            sq[j] = s * HID;
            wq[j] = make_float4(wx, wy, wz, ww);
        }
        for (int j = m + ol; j < mm8; j += 8) {
            sq[j] = N_NODES * HID;
            wq[j] = make_float4(0.f, 0.f, 0.f, 0.f);
        }
        // consume: 8 independent 16B gathers in flight; weights read from LDS at use
        for (int i0 = 0; i0 < mm8; i0 += 8) {
            float4 raw[8];
#pragma unroll
            for (int k = 0; k < 8; k++)
                raw[k] = *(const float4*)(hp + sq[i0 + k]);
#pragma unroll
            for (int k = 0; k < 8; k++) {
                float4 w4 = wq[i0 + k];
                __half2 g0 = __builtin_bit_cast(__half2, raw[k].x);
                __half2 g1 = __builtin_bit_cast(__half2, raw[k].y);
                __half2 g2 = __builtin_bit_cast(__half2, raw[k].z);
                __half2 g3 = __builtin_bit_cast(__half2, raw[k].w);
                float2 f0 = __half22float2(g0), f1 = __half22float2(g1);
                float2 f2 = __half22float2(g2), f3 = __half22float2(g3);
                f32x4 flo = {f0.x, f0.y, f1.x, f1.y};
                f32x4 fhi = {f2.x, f2.y, f3.x, f3.y};
                f32x4 wxv = {w4.x, w4.x, w4.x, w4.x};
                f32x4 wyv = {w4.y, w4.y, w4.y, w4.y};
                f32x4 wzv = {w4.z, w4.z, w4.z, w4.z};
                f32x4 wwv = {w4.w, w4.w, w4.w, w4.w};
                accA[0] += wxv * flo; accB[0] += wxv * fhi;
                accA[1] += wyv * flo; accB[1] += wyv * fhi;
                accA[2] += wzv * flo; accB[2] += wzv * fhi;
                accA[3] += wwv * flo; accB[3] += wwv * fhi;
            }
        }
    }
    // reduce denominators within the octet (lanes hold disjoint edge subsets)
#pragma unroll
    for (int off = 4; off > 0; off >>= 1) {
        dnx += __shfl_xor(dnx, off);
        dny += __shfl_xor(dny, off);
        dnz += __shfl_xor(dnz, off);
        dnw += __shfl_xor(dnw, off);
    }
    // self-loop: w_self per head (uniform within octet)
    float4 asn = *(const float4*)&a_s[nn * 4];
    float sx = asn.x + ad4.x; sx = fmaxf(sx, NEG_SLOPE * sx);
    float sy = asn.y + ad4.y; sy = fmaxf(sy, NEG_SLOPE * sy);
    float sz = asn.z + ad4.z; sz = fmaxf(sz, NEG_SLOPE * sz);
    float sw = asn.w + ad4.w; sw = fmaxf(sw, NEG_SLOPE * sw);
    float wsx = __expf(sx), wsy = __expf(sy);
    float wsz = __expf(sz), wsw = __expf(sw);
    dnx += wsx; dny += wsy; dnz += wsz; dnw += wsw;
    {
        float4 raw = *(const float4*)(hp + nn * HID);
        __half2 g0 = __builtin_bit_cast(__half2, raw.x);
        __half2 g1 = __builtin_bit_cast(__half2, raw.y);
        __half2 g2 = __builtin_bit_cast(__half2, raw.z);
        __half2 g3 = __builtin_bit_cast(__half2, raw.w);
        float2 f0 = __half22float2(g0), f1 = __half22float2(g1);
        float2 f2 = __half22float2(g2), f3 = __half22float2(g3);
        f32x4 flo = {f0.x, f0.y, f1.x, f1.y};
        f32x4 fhi = {f2.x, f2.y, f3.x, f3.y};
        accA[0] += (f32x4){wsx,wsx,wsx,wsx} * flo; accB[0] += (f32x4){wsx,wsx,wsx,wsx} * fhi;
        accA[1] += (f32x4){wsy,wsy,wsy,wsy} * flo; accB[1] += (f32x4){wsy,wsy,wsy,wsy} * fhi;
        accA[2] += (f32x4){wsz,wsz,wsz,wsz} * flo; accB[2] += (f32x4){wsz,wsz,wsz,wsz} * fhi;
        accA[3] += (f32x4){wsw,wsw,wsw,wsw} * flo; accB[3] += (f32x4){wsw,wsw,wsw,wsw} * fhi;
    }
    if (n < N_NODES) {
        float r4[4] = {1.f / dnx, 1.f / dny, 1.f / dnz, 1.f / dnw};
        __half* up = u + (size_t)n * 256 + ol * 8;
#pragma unroll
        for (int hh = 0; hh < 4; hh++) {
            float r = r4[hh];
            __half2 p0 = __floats2half2_rn(accA[hh].x * r, accA[hh].y * r);
            __half2 p1 = __floats2half2_rn(accA[hh].z * r, accA[hh].w * r);
            __half2 p2 = __floats2half2_rn(accB[hh].x * r, accB[hh].y * r);
            __half2 p3 = __floats2half2_rn(accB[hh].z * r, accB[hh].w * r);
            float4 pk;
            pk.x = __builtin_bit_cast(float, p0);
            pk.y = __builtin_bit_cast(float, p1);
            pk.z = __builtin_bit_cast(float, p2);
            pk.w = __builtin_bit_cast(float, p3);
            *(float4*)&up[hh * 64] = pk;           // 16B store per head
        }
    }
}

// ---------------------------------------------------------------- gemm23 (MFMA, fused): out = relu(u @ blockdiag(W_gat) + b_gat) @ W_fc + b_fc
// R17: h2 (25.6MB) never touches HBM. Per block: 64 rows (4 tiles).
// Phase 1 (== gemm2b math): wave hd computes cols [hd*64, hd*64+64) for all 4 tiles -> LDS.
// Phase 2 (== gemm3 math): wave w computes out for tile t0+w, A from LDS (row stride 264
// halves = 132 dwords ≡ 4 banks -> 2-way conflict, free).
__global__ __launch_bounds__(256) void gemm23(const __half* __restrict__ u,
                                              const float* __restrict__ Wg,
                                              const float* __restrict__ bg,
                                              const float* __restrict__ Wf,
                                              const float* __restrict__ bf,
                                              float* __restrict__ out) {
    __shared__ __half h2s[64][264];       // 33.8 KB
    int lane = threadIdx.x & 63, hd = threadIdx.x >> 6;
    int quad = lane >> 4, l16 = lane & 15;
    // W_gat fragments for this wave's head
    half8 Bg[4][2];
#pragma unroll
    for (int nt = 0; nt < 4; nt++)
#pragma unroll
        for (int kc = 0; kc < 2; kc++) {
            const float* wp = Wg + (kc * 32 + quad * 8) * 256 + hd * 64 + nt * 16 + l16;
#pragma unroll
            for (int j = 0; j < 8; j++)
                Bg[nt][kc][j] = (_Float16)wp[j * 256];
        }
    float bbg[4];
#pragma unroll
    for (int nt = 0; nt < 4; nt++) bbg[nt] = bg[hd * 64 + nt * 16 + l16];
    // W_fc fragments (every wave)
    half8 Bf[2][8];
#pragma unroll
    for (int nt = 0; nt < 2; nt++)
#pragma unroll
        for (int kc = 0; kc < 8; kc++) {
            const float* wp = Wf + (kc * 32 + quad * 8) * 32 + nt * 16 + l16;
#pragma unroll
            for (int j = 0; j < 8; j++)
                Bf[nt][kc][j] = (_Float16)wp[j * 32];
        }
    float bb0 = bf[l16], bb1 = bf[16 + l16];

    int t0 = blockIdx.x * 4;
    // phase 1: h2 tile (64 rows x 256 cols) into LDS; wave hd owns 64 cols
#pragma unroll
    for (int i = 0; i < 4; i++) {
        int rt = t0 + i;
        if (rt >= NTILES) break;              // block-uniform
        const __half* up = u + ((size_t)(rt * 16 + l16)) * 256 + hd * 64 + quad * 8;
        half8 A0 = *(const half8*)(const void*)up;
        half8 A1 = *(const half8*)(const void*)(up + 32);
        f32x4 acc[4];
#pragma unroll
        for (int nt = 0; nt < 4; nt++) {
            acc[nt] = (f32x4){0.f, 0.f, 0.f, 0.f};
            acc[nt] = __builtin_amdgcn_mfma_f32_16x16x32_f16(A0, Bg[nt][0], acc[nt], 0, 0, 0);
            acc[nt] = __builtin_amdgcn_mfma_f32_16x16x32_f16(A1, Bg[nt][1], acc[nt], 0, 0, 0);
        }
#pragma unroll
        for (int nt = 0; nt < 4; nt++) {
            int col = hd * 64 + nt * 16 + l16;
#pragma unroll
            for (int reg = 0; reg < 4; reg++)
                h2s[i * 16 + quad * 4 + reg][col] = __float2half(fmaxf(acc[nt][reg] + bbg[nt], 0.f));
        }
    }
    __syncthreads();
    // phase 2: wave hd -> tile t0+hd
    int rt = t0 + hd;
    if (rt < NTILES) {
        f32x4 acc0 = {0.f, 0.f, 0.f, 0.f};
        f32x4 acc1 = {0.f, 0.f, 0.f, 0.f};
#pragma unroll
        for (int kc = 0; kc < 8; kc++) {
            half8 A = *(const half8*)(const void*)&h2s[hd * 16 + l16][kc * 32 + quad * 8];
            acc0 = __builtin_amdgcn_mfma_f32_16x16x32_f16(A, Bf[0][kc], acc0, 0, 0, 0);
            acc1 = __builtin_amdgcn_mfma_f32_16x16x32_f16(A, Bf[1][kc], acc1, 0, 0, 0);
        }
#pragma unroll
        for (int reg = 0; reg < 4; reg++) {
            int row = rt * 16 + quad * 4 + reg;
            out[row * 32 + l16]      = acc0[reg] + bb0;
            out[row * 32 + 16 + l16] = acc1[reg] + bb1;
        }
    }
}

// ---------------------------------------------------------------- launch
extern "C" void kernel_launch(void* const* d_in, const int* in_sizes, int n_in,
                              void* d_out, int out_size, void* d_ws, size_t ws_size,
                              hipStream_t stream) {
    const float* x      = (const float*)d_in[0];
    const int*   edge   = (const int*)  d_in[1];
    const float* W_gcn  = (const float*)d_in[2];
    const float* b_gcn  = (const float*)d_in[3];
    const float* W_gat  = (const float*)d_in[4];
    const float* att_s  = (const float*)d_in[5];
    const float* att_d  = (const float*)d_in[6];
    const float* b_gat  = (const float*)d_in[7];
    const float* W_fc   = (const float*)d_in[8];
    const float* b_fc   = (const float*)d_in[9];
    float* out = (float*)d_out;

    char* p = (char*)d_ws;
    auto alloc = [&](size_t bytes) {
        char* q = p;
        p += (bytes + 255) & ~(size_t)255;
        return q;
    };
    __half* h     = (__half*)alloc((size_t)(N_NODES + 1) * HID * 2);   // +1 zero row
    __half* h1    = (__half*)alloc((size_t)(N_NODES + 1) * HID * 2);   // +1 zero row
    __half* u     = (__half*)alloc((size_t)N_NODES * 256 * 2);
    float* as_a   = (float*)alloc((size_t)N_NODES * 4 * 4);
    float* ad_a   = (float*)alloc((size_t)N_NODES * 4 * 4);
    float* dinv   = (float*)alloc((size_t)N_NODES * 4);
    int*   rowptr = (int*)  alloc((size_t)(N_NODES + 1) * 4);
    unsigned short* colidx = (unsigned short*)alloc((size_t)N_EDGES * 2);
    int*   ghist  = (int*)  alloc((size_t)GH * 4);
    int*   bsum   = (int*)  alloc((size_t)NSB * 4);
    unsigned* tmp = (unsigned*)alloc((size_t)N_EDGES * 4);
    float* vsrc   = (float*)alloc((size_t)HEADS * HID * 4);
    float* vdst   = (float*)alloc((size_t)HEADS * HID * 4);

    // CSR build: atomic-free MSD bucket sort (hierarchical coalesced scan; attvec fused into scanB2)
    histA        <<<NBLK_A, 256, 0, stream>>>(edge, ghist);
    scanB1       <<<NSB, 256, 0, stream>>>(ghist, bsum);
    scanB2_attvec<<<2, 320, 0, stream>>>(bsum, W_gat, att_s, att_d, vsrc, vdst);
    scanB3       <<<NSB, 256, 0, stream>>>(ghist, bsum);
    scatterC     <<<NBLK_A, 256, 0, stream>>>(edge, ghist, tmp);
    sortD        <<<NBKT, 256, 0, stream>>>(tmp, ghist, colidx, rowptr, dinv);

    // GCN (gemm1 also zeroes the pad rows of h/h1)
    gemm1   <<<(N_NODES + 31) / 32, 256, 0, stream>>>(x, W_gcn, dinv, h, h1);
    gcn_agg <<<(N_NODES + 31) / 32, 256, 0, stream>>>(h, rowptr, colidx, dinv, b_gcn,
                                                      vsrc, vdst, h1, as_a, ad_a);

    // GAT
    gat_agg <<<(N_NODES + 31) / 32, 256, 0, stream>>>(h1, rowptr, colidx, as_a, ad_a, u);

    // fused GAT-linear + FC (h2 stays in LDS)
    gemm23  <<<(NTILES + 3) / 4, 256, 0, stream>>>(u, W_gat, b_gat, W_fc, b_fc, out);
}

// Round 8
// 207.956 us; speedup vs baseline: 1.1681x; 1.0316x over previous
//
#include <hip/hip_runtime.h>
#include <hip/hip_bf16.h>
#include <hip/hip_fp16.h>
#include <math.h>

#define N_NODES 50000
#define N_EDGES 1600000
#define D_IN    32
#define HID     64
#define HEADS   4
#define D_OUT   32
#define NEG_SLOPE 0.2f
#define NTILES 3125   // N_NODES / 16, exact

// per-octet edge chunks (deg ~ Poisson(32))
#define CQG 64        // gcn_agg
#define CQA 32        // gat_agg (wbuf LDS budget) — R5 verified two-phase structure

// MSD bucket-sort CSR build
#define NBKT 196      // d>>8 buckets (d < 50000)
#define NBLK_A 391    // ceil(1.6M / 4096)
#define TILE_A 4096
#define GH (NBKT * NBLK_A)   // 76636
#define NSB 300       // ceil(GH / 256)
#define CAP 10240     // max bucket size (avg 8163, sigma ~90 -> 23 sigma margin)

typedef _Float16 half8 __attribute__((ext_vector_type(8)));
typedef float    f32x4 __attribute__((ext_vector_type(4)));
typedef float    f32x2 __attribute__((ext_vector_type(2)));

// ---------------------------------------------------------------- CSR: pass A — per-block 196-bin histogram (LDS, per-wave replicas)
__global__ __launch_bounds__(256) void histA(const int* __restrict__ edge,
                                             int* __restrict__ ghist) {
    __shared__ int hist[4][NBKT];
    int t = threadIdx.x, wv = t >> 6;
    for (int i = t; i < 4 * NBKT; i += 256) ((int*)hist)[i] = 0;
    __syncthreads();
    int base = blockIdx.x * TILE_A;
#pragma unroll
    for (int k = 0; k < 16; k++) {
        int i = base + k * 256 + t;
        if (i < N_EDGES) atomicAdd(&hist[wv][edge[N_EDGES + i] >> 8], 1);
    }
    __syncthreads();
    for (int b = t; b < NBKT; b += 256)
        ghist[b * NBLK_A + blockIdx.x] = hist[0][b] + hist[1][b] + hist[2][b] + hist[3][b];
}

// ---------------------------------------------------------------- CSR: pass B — hierarchical coalesced scan of GH entries
__global__ __launch_bounds__(256) void scanB1(const int* __restrict__ g,
                                              int* __restrict__ bsum) {
    int t = threadIdx.x;
    int i = blockIdx.x * 256 + t;
    int v = (i < GH) ? g[i] : 0;              // coalesced
#pragma unroll
    for (int off = 32; off; off >>= 1) v += __shfl_xor(v, off);
    __shared__ int ws[4];
    if ((t & 63) == 0) ws[t >> 6] = v;
    __syncthreads();
    if (t == 0) bsum[blockIdx.x] = ws[0] + ws[1] + ws[2] + ws[3];
}

// block 0: scan of NSB block sums.  block 1: attention projection vectors (fused to save a launch).
__global__ __launch_bounds__(320) void scanB2_attvec(int* __restrict__ bsum,
                                                     const float* __restrict__ W,
                                                     const float* __restrict__ att_s,
                                                     const float* __restrict__ att_d,
                                                     float* __restrict__ vsrc,
                                                     float* __restrict__ vdst) {
    int t = threadIdx.x, lane = t & 63, wv = t >> 6;
    if (blockIdx.x == 0) {
        int v = (t < NSB) ? bsum[t] : 0;
        int inc = v;
#pragma unroll
        for (int d = 1; d < 64; d <<= 1) {
            int u = __shfl_up(inc, d);
            if (lane >= d) inc += u;
        }
        __shared__ int ws[5];
        if (lane == 63) ws[wv] = inc;
        __syncthreads();
        int add = 0;
#pragma unroll
        for (int j = 0; j < 5; j++) if (j < wv) add += ws[j];
        if (t < NSB) bsum[t] = add + inc - v;     // exclusive block offsets
    } else if (t < 256) {
        int h = t >> 6, k = t & 63;
        float s_ = 0.f, d_ = 0.f;
#pragma unroll 8
        for (int c = 0; c < 64; c++) {
            float w = W[k * 256 + h * 64 + c];
            s_ += w * att_s[h * 64 + c];
            d_ += w * att_d[h * 64 + c];
        }
        vsrc[h * 64 + k] = s_;
        vdst[h * 64 + k] = d_;
    }
}

__global__ __launch_bounds__(256) void scanB3(int* __restrict__ g,
                                              const int* __restrict__ bsum) {
    int t = threadIdx.x, lane = t & 63, wv = t >> 6;
    int i = blockIdx.x * 256 + t;
    int v = (i < GH) ? g[i] : 0;              // coalesced
    int inc = v;
#pragma unroll
    for (int d = 1; d < 64; d <<= 1) {
        int u = __shfl_up(inc, d);
        if (lane >= d) inc += u;
    }
    __shared__ int ws[4];
    if (lane == 63) ws[wv] = inc;
    __syncthreads();
    int add = 0;
#pragma unroll
    for (int j = 0; j < 4; j++) if (j < wv) add += ws[j];
    if (i < GH) g[i] = bsum[blockIdx.x] + add + inc - v;   // exclusive prefix
}

// ---------------------------------------------------------------- CSR: pass C — scatter packed (d<<16|s) via LDS cursors (disjoint global ranges)
// R18: 512 threads (8 serial iters instead of 16) — grid 391 can't fill more blocks/CU,
// so widen within the block.
__global__ __launch_bounds__(512) void scatterC(const int* __restrict__ edge,
                                                const int* __restrict__ ghist,
                                                unsigned* __restrict__ tmp) {
    __shared__ int cur[NBKT];
    int t = threadIdx.x;
    if (t < NBKT) cur[t] = ghist[t * NBLK_A + blockIdx.x];
    __syncthreads();
    int base = blockIdx.x * TILE_A;
#pragma unroll
    for (int k = 0; k < 8; k++) {
        int i = base + k * 512 + t;
        if (i < N_EDGES) {
            int s = edge[i], d = edge[N_EDGES + i];
            int pos = atomicAdd(&cur[d >> 8], 1);     // LDS atomic
            tmp[pos] = ((unsigned)d << 16) | (unsigned)s;
        }
    }
}

// ---------------------------------------------------------------- CSR: pass D — per-bucket 256-bin regroup; emits colidx(u16), rowptr, dinv
// R18: 512 threads — sortD is the only kernel with <1 block/CU (196 blocks, 23% of CUs idle);
// halve every serial per-thread loop (32 -> 16 iters). Rank order within a bin becomes
// non-stable: harmless (edge order within a CSR row is irrelevant to the aggs).
__global__ __launch_bounds__(512) void sortD(const unsigned* __restrict__ tmp,
                                             const int* __restrict__ ghist,
                                             unsigned short* __restrict__ colidx,
                                             int* __restrict__ rowptr,
                                             float* __restrict__ dinv) {
    __shared__ unsigned char  dl8[CAP];
    __shared__ unsigned short s16[CAP];
    __shared__ unsigned short o16[CAP];
    __shared__ int hist[8][256];
    __shared__ int excl[256];
    __shared__ int wsum[4];
    int t = threadIdx.x, lane = t & 63, wv = t >> 6;   // wv 0..7
    int b = blockIdx.x;
    int lo = ghist[b * NBLK_A];
    int hi = (b < NBKT - 1) ? ghist[(b + 1) * NBLK_A] : N_EDGES;
    int size = hi - lo;
    if (size > CAP) size = CAP;           // unreachable safety clamp
    for (int i = t; i < 8 * 256; i += 512) ((int*)hist)[i] = 0;
    __syncthreads();
    for (int i = t; i < size; i += 512) {
        unsigned key = tmp[lo + i];
        int dl = (key >> 16) & 255;
        dl8[i] = (unsigned char)dl;
        s16[i] = (unsigned short)(key & 0xFFFF);
        atomicAdd(&hist[wv][dl], 1);
    }
    __syncthreads();
    // block scan over 256 bins on the first 4 waves
    int h = 0, inc = 0;
    if (t < 256) {
        h = hist[0][t] + hist[1][t] + hist[2][t] + hist[3][t]
          + hist[4][t] + hist[5][t] + hist[6][t] + hist[7][t];
        inc = h;
#pragma unroll
        for (int d = 1; d < 64; d <<= 1) {
            int u = __shfl_up(inc, d);
            if (lane >= d) inc += u;
        }
        if (lane == 63) wsum[wv] = inc;
    }
    __syncthreads();
    if (t < 256) {
        int add = 0;
#pragma unroll
        for (int j = 0; j < 4; j++) if (j < wv) add += wsum[j];
        int ex = inc - h + add;
        excl[t] = ex;
        int node = b * 256 + t;
        if (node < N_NODES) {
            rowptr[node] = lo + ex;
            dinv[node]   = rsqrtf((float)(h + 1));        // +1 self-loop
        }
    }
    if (b == NBKT - 1 && t == 0) rowptr[N_NODES] = N_EDGES;
    __syncthreads();
    for (int i = t; i < size; i += 512) {
        int pos = atomicAdd(&excl[dl8[i]], 1);        // LDS cursor claim
        o16[pos] = s16[i];
    }
    __syncthreads();
    for (int i = t; i < size; i += 512) colidx[lo + i] = o16[i];
}

// ---------------------------------------------------------------- GEMM1: h = fp16( dinv .* (x @ W_gcn) ); block 0 zeros the pad rows
__global__ __launch_bounds__(256) void gemm1(const float* __restrict__ x,
                                             const float* __restrict__ W,
                                             const float* __restrict__ dinv,
                                             __half* __restrict__ h,
                                             __half* __restrict__ h1) {
    __shared__ float Wl[D_IN * HID];      // 8 KB
    int t = threadIdx.x;
    if (blockIdx.x == 0 && t < HID) {     // zero pad row N_NODES (read by pad lanes in agg kernels)
        h [(size_t)N_NODES * HID + t] = __float2half(0.f);
        h1[(size_t)N_NODES * HID + t] = __float2half(0.f);
    }
    for (int i = t; i < D_IN * HID; i += 256) Wl[i] = W[i];
    __syncthreads();
    int c = t & 63, rw = t >> 6;
    int r0 = blockIdx.x * 32;
#pragma unroll
    for (int rr = 0; rr < 8; rr++) {
        int r = r0 + rr * 4 + rw;
        if (r >= N_NODES) break;
        const float4* xr4 = (const float4*)(x + r * D_IN);
        float acc = 0.f;
#pragma unroll
        for (int k4 = 0; k4 < D_IN / 4; k4++) {
            float4 xv = xr4[k4];
            int k = k4 * 4;
            acc += xv.x * Wl[(k+0)*HID + c] + xv.y * Wl[(k+1)*HID + c]
                 + xv.z * Wl[(k+2)*HID + c] + xv.w * Wl[(k+3)*HID + c];
        }
        h[r * HID + c] = __float2half(acc * dinv[r]);
    }
}

// ---------------------------------------------------------------- GCN aggregate -> h1 fp16 (relu), fused attention dots
// Octet layout (R15, verified): 8 lanes/node, lane holds 8 channels (float4 = 16B gather).
__global__ __launch_bounds__(256) void gcn_agg(const __half* __restrict__ h,
                                               const int* __restrict__ rowptr,
                                               const unsigned short* __restrict__ colidx,
                                               const float* __restrict__ dinv,
                                               const float* __restrict__ b,
                                               const float* __restrict__ vsrc,
                                               const float* __restrict__ vdst,
                                               __half* __restrict__ h1,
                                               float* __restrict__ as_o,
                                               float* __restrict__ ad_o) {
    __shared__ int sbuf[4][8][CQG + 1];   // 8.3 KB
    int lane = threadIdx.x & 63, wv = threadIdx.x >> 6;
    int oct = lane >> 3, ol = lane & 7;
    int n = blockIdx.x * 32 + wv * 8 + oct;
    int nn = min(n, N_NODES - 1);
    int rp = rowptr[nn], re = rowptr[nn + 1];
    int deg = (n < N_NODES) ? (re - rp) : 0;
    int dm = deg;                                  // max degree across the wave's 8 octets
    dm = max(dm, __shfl_xor(dm, 8));
    dm = max(dm, __shfl_xor(dm, 16));
    dm = max(dm, __shfl_xor(dm, 32));
    f32x4 a0 = {0.f,0.f,0.f,0.f}, a1 = {0.f,0.f,0.f,0.f};   // 8 channels
    const __half* hp = h + ol * 8;
    int* sq = sbuf[wv][oct];
    for (int cb = 0; cb < dm; cb += CQG) {
        int m  = min(CQG, max(deg - cb, 0));
        int mm = min(CQG, dm - cb);
        int mm8 = (mm + 7) & ~7;                   // <= CQG
        // stage source offsets: 8-lane stride per octet (all 64 lanes active)
        for (int j = ol; j < m; j += 8)
            sq[j] = (int)colidx[rp + cb + j] * HID;
        for (int j = m + ol; j < mm8; j += 8)
            sq[j] = N_NODES * HID;                 // zero row pad
        // consume: 8 independent 16B gathers in flight (8 rows/instr across octets)
        for (int i0 = 0; i0 < mm8; i0 += 8) {
            float4 raw[8];
#pragma unroll
            for (int k = 0; k < 8; k++)
                raw[k] = *(const float4*)(hp + sq[i0 + k]);   // uniform within octet
#pragma unroll
            for (int k = 0; k < 8; k++) {
                __half2 g0 = __builtin_bit_cast(__half2, raw[k].x);
                __half2 g1 = __builtin_bit_cast(__half2, raw[k].y);
                __half2 g2 = __builtin_bit_cast(__half2, raw[k].z);
                __half2 g3 = __builtin_bit_cast(__half2, raw[k].w);
                float2 f0 = __half22float2(g0), f1 = __half22float2(g1);
                float2 f2 = __half22float2(g2), f3 = __half22float2(g3);
                a0.x += f0.x; a0.y += f0.y; a0.z += f1.x; a0.w += f1.y;
                a1.x += f2.x; a1.y += f2.y; a1.z += f3.x; a1.w += f3.y;
            }
        }
    }
    // self-loop contribution (h pre-scaled by dinv[n])
    {
        float4 raw = *(const float4*)(hp + nn * HID);
        __half2 g0 = __builtin_bit_cast(__half2, raw.x);
        __half2 g1 = __builtin_bit_cast(__half2, raw.y);
        __half2 g2 = __builtin_bit_cast(__half2, raw.z);
        __half2 g3 = __builtin_bit_cast(__half2, raw.w);
        float2 f0 = __half22float2(g0), f1 = __half22float2(g1);
        float2 f2 = __half22float2(g2), f3 = __half22float2(g3);
        a0.x += f0.x; a0.y += f0.y; a0.z += f1.x; a0.w += f1.y;
        a1.x += f2.x; a1.y += f2.y; a1.z += f3.x; a1.w += f3.y;
    }
    float dn = dinv[nn];
    const float4 bb0 = *(const float4*)&b[ol * 8];
    const float4 bb1 = *(const float4*)&b[ol * 8 + 4];
    float v0 = fmaxf(a0.x * dn + bb0.x, 0.f);
    float v1 = fmaxf(a0.y * dn + bb0.y, 0.f);
    float v2 = fmaxf(a0.z * dn + bb0.z, 0.f);
    float v3 = fmaxf(a0.w * dn + bb0.w, 0.f);
    float v4 = fmaxf(a1.x * dn + bb1.x, 0.f);
    float v5 = fmaxf(a1.y * dn + bb1.y, 0.f);
    float v6 = fmaxf(a1.z * dn + bb1.z, 0.f);
    float v7 = fmaxf(a1.w * dn + bb1.w, 0.f);
    if (n < N_NODES) {
        __half2 p0 = __floats2half2_rn(v0, v1);
        __half2 p1 = __floats2half2_rn(v2, v3);
        __half2 p2 = __floats2half2_rn(v4, v5);
        __half2 p3 = __floats2half2_rn(v6, v7);
        float4 pk;
        pk.x = __builtin_bit_cast(float, p0);
        pk.y = __builtin_bit_cast(float, p1);
        pk.z = __builtin_bit_cast(float, p2);
        pk.w = __builtin_bit_cast(float, p3);
        *(float4*)&h1[n * HID + ol * 8] = pk;      // 16B store
    }
    // attention dots: reduce within the 8-lane octet (serves 8 nodes at once)
#pragma unroll
    for (int hh = 0; hh < 4; hh++) {
        const float4 s0 = *(const float4*)&vsrc[hh * 64 + ol * 8];
        const float4 s1 = *(const float4*)&vsrc[hh * 64 + ol * 8 + 4];
        const float4 d0 = *(const float4*)&vdst[hh * 64 + ol * 8];
        const float4 d1 = *(const float4*)&vdst[hh * 64 + ol * 8 + 4];
        float vs = v0*s0.x + v1*s0.y + v2*s0.z + v3*s0.w
                 + v4*s1.x + v5*s1.y + v6*s1.z + v7*s1.w;
        float vd = v0*d0.x + v1*d0.y + v2*d0.z + v3*d0.w
                 + v4*d1.x + v5*d1.y + v6*d1.z + v7*d1.w;
#pragma unroll
        for (int off = 4; off > 0; off >>= 1) {
            vs += __shfl_xor(vs, off);
            vd += __shfl_xor(vd, off);
        }
        if (ol == 0 && n < N_NODES) {
            as_o[n * 4 + hh] = vs;
            ad_o[n * 4 + hh] = vd;
        }
    }
}

// ---------------------------------------------------------------- GAT aggregate (no max pass; self-loop analytic) -> u fp16
// R5-verified two-phase octet layout: 8 lanes/node, lane holds 8 channels; 1KB gathered
// per wave instr. Weight phase at 8-lane stride; denominators reduced over 8 lanes.
__global__ __launch_bounds__(256) void gat_agg(const __half* __restrict__ h1,
                                               const int* __restrict__ rowptr,
                                               const unsigned short* __restrict__ colidx,
                                               const float* __restrict__ a_s,
                                               const float* __restrict__ a_d,
                                               __half* __restrict__ u) {
    __shared__ float4 wbuf[4][8][CQA + 1];   // 16.9 KB
    __shared__ int    sbuf[4][8][CQA + 1];   //  4.2 KB
    int lane = threadIdx.x & 63, wv = threadIdx.x >> 6;
    int oct = lane >> 3, ol = lane & 7;
    int n = blockIdx.x * 32 + wv * 8 + oct;
    int nn = min(n, N_NODES - 1);
    int rp = rowptr[nn], re = rowptr[nn + 1];
    int deg = (n < N_NODES) ? (re - rp) : 0;
    int dm = deg;
    dm = max(dm, __shfl_xor(dm, 8));
    dm = max(dm, __shfl_xor(dm, 16));
    dm = max(dm, __shfl_xor(dm, 32));
    float4 ad4 = *(const float4*)&a_d[nn * 4];

    float dnx = 0.f, dny = 0.f, dnz = 0.f, dnw = 0.f;
    f32x4 accA[4], accB[4];                  // [head][ch 0-3], [head][ch 4-7]
#pragma unroll
    for (int hh = 0; hh < 4; hh++) { accA[hh] = (f32x4){0.f,0.f,0.f,0.f}; accB[hh] = (f32x4){0.f,0.f,0.f,0.f}; }
    const __half* hp = h1 + ol * 8;
    int*    sq = sbuf[wv][oct];
    float4* wq = wbuf[wv][oct];
    for (int cb = 0; cb < dm; cb += CQA) {
        int m  = min(CQA, max(deg - cb, 0));
        int mm = min(CQA, dm - cb);
        int mm8 = (mm + 7) & ~7;                   // <= CQA
        // phase B: weights at 8-lane stride per octet (no clamp: logits are O(+-6), fp32 exp safe)
        for (int j = ol; j < m; j += 8) {
            int s = colidx[rp + cb + j];
            float4 a = *(const float4*)&a_s[s * 4];
            float vx = a.x + ad4.x; vx = fmaxf(vx, NEG_SLOPE * vx);
            float vy = a.y + ad4.y; vy = fmaxf(vy, NEG_SLOPE * vy);
            float vz = a.z + ad4.z; vz = fmaxf(vz, NEG_SLOPE * vz);
            float vw = a.w + ad4.w; vw = fmaxf(vw, NEG_SLOPE * vw);
            float wx = __expf(vx), wy = __expf(vy);
            float wz = __expf(vz), ww = __expf(vw);
            dnx += wx; dny += wy; dnz += wz; dnw += ww;
            sq[j] = s * HID;
            wq[j] = make_float4(wx, wy, wz, ww);
        }
        for (int j = m + ol; j < mm8; j += 8) {
            sq[j] = N_NODES * HID;
            wq[j] = make_float4(0.f, 0.f, 0.f, 0.f);
        }
        // consume: 8 independent 16B gathers in flight; weights read from LDS at use
        for (int i0 = 0; i0 < mm8; i0 += 8) {
            float4 raw[8];
#pragma unroll
            for (int k = 0; k < 8; k++)
                raw[k] = *(const float4*)(hp + sq[i0 + k]);
#pragma unroll
            for (int k = 0; k < 8; k++) {
                float4 w4 = wq[i0 + k];
                __half2 g0 = __builtin_bit_cast(__half2, raw[k].x);
                __half2 g1 = __builtin_bit_cast(__half2, raw[k].y);
                __half2 g2 = __builtin_bit_cast(__half2, raw[k].z);
                __half2 g3 = __builtin_bit_cast(__half2, raw[k].w);
                float2 f0 = __half22float2(g0), f1 = __half22float2(g1);
                float2 f2 = __half22float2(g2), f3 = __half22float2(g3);
                f32x4 flo = {f0.x, f0.y, f1.x, f1.y};
                f32x4 fhi = {f2.x, f2.y, f3.x, f3.y};
                f32x4 wxv = {w4.x, w4.x, w4.x, w4.x};
                f32x4 wyv = {w4.y, w4.y, w4.y, w4.y};
                f32x4 wzv = {w4.z, w4.z, w4.z, w4.z};
                f32x4 wwv = {w4.w, w4.w, w4.w, w4.w};
                accA[0] += wxv * flo; accB[0] += wxv * fhi;
                accA[1] += wyv * flo; accB[1] += wyv * fhi;
                accA[2] += wzv * flo; accB[2] += wzv * fhi;
                accA[3] += wwv * flo; accB[3] += wwv * fhi;
            }
        }
    }
    // reduce denominators within the octet (lanes hold disjoint edge subsets)
#pragma unroll
    for (int off = 4; off > 0; off >>= 1) {
        dnx += __shfl_xor(dnx, off);
        dny += __shfl_xor(dny, off);
        dnz += __shfl_xor(dnz, off);
        dnw += __shfl_xor(dnw, off);
    }
    // self-loop: w_self per head (uniform within octet)
    float4 asn = *(const float4*)&a_s[nn * 4];
    float sx = asn.x + ad4.x; sx = fmaxf(sx, NEG_SLOPE * sx);
    float sy = asn.y + ad4.y; sy = fmaxf(sy, NEG_SLOPE * sy);
    float sz = asn.z + ad4.z; sz = fmaxf(sz, NEG_SLOPE * sz);
    float sw = asn.w + ad4.w; sw = fmaxf(sw, NEG_SLOPE * sw);
    float wsx = __expf(sx), wsy = __expf(sy);
    float wsz = __expf(sz), wsw = __expf(sw);
    dnx += wsx; dny += wsy; dnz += wsz; dnw += wsw;
    {
        float4 raw = *(const float4*)(hp + nn * HID);
        __half2 g0 = __builtin_bit_cast(__half2, raw.x);
        __half2 g1 = __builtin_bit_cast(__half2, raw.y);
        __half2 g2 = __builtin_bit_cast(__half2, raw.z);
        __half2 g3 = __builtin_bit_cast(__half2, raw.w);
        float2 f0 = __half22float2(g0), f1 = __half22float2(g1);
        float2 f2 = __half22float2(g2), f3 = __half22float2(g3);
        f32x4 flo = {f0.x, f0.y, f1.x, f1.y};
        f32x4 fhi = {f2.x, f2.y, f3.x, f3.y};
        accA[0] += (f32x4){wsx,wsx,wsx,wsx} * flo; accB[0] += (f32x4){wsx,wsx,wsx,wsx} * fhi;
        accA[1] += (f32x4){wsy,wsy,wsy,wsy} * flo; accB[1] += (f32x4){wsy,wsy,wsy,wsy} * fhi;
        accA[2] += (f32x4){wsz,wsz,wsz,wsz} * flo; accB[2] += (f32x4){wsz,wsz,wsz,wsz} * fhi;
        accA[3] += (f32x4){wsw,wsw,wsw,wsw} * flo; accB[3] += (f32x4){wsw,wsw,wsw,wsw} * fhi;
    }
    if (n < N_NODES) {
        float r4[4] = {1.f / dnx, 1.f / dny, 1.f / dnz, 1.f / dnw};
        __half* up = u + (size_t)n * 256 + ol * 8;
#pragma unroll
        for (int hh = 0; hh < 4; hh++) {
            float r = r4[hh];
            __half2 p0 = __floats2half2_rn(accA[hh].x * r, accA[hh].y * r);
            __half2 p1 = __floats2half2_rn(accA[hh].z * r, accA[hh].w * r);
            __half2 p2 = __floats2half2_rn(accB[hh].x * r, accB[hh].y * r);
            __half2 p3 = __floats2half2_rn(accB[hh].z * r, accB[hh].w * r);
            float4 pk;
            pk.x = __builtin_bit_cast(float, p0);
            pk.y = __builtin_bit_cast(float, p1);
            pk.z = __builtin_bit_cast(float, p2);
            pk.w = __builtin_bit_cast(float, p3);
            *(float4*)&up[hh * 64] = pk;           // 16B store per head
        }
    }
}

// ---------------------------------------------------------------- gemm23 (MFMA, fused): out = relu(u @ blockdiag(W_gat) + b_gat) @ W_fc + b_fc
// R17: h2 (25.6MB) never touches HBM. Per block: 64 rows (4 tiles).
__global__ __launch_bounds__(256) void gemm23(const __half* __restrict__ u,
                                              const float* __restrict__ Wg,
                                              const float* __restrict__ bg,
                                              const float* __restrict__ Wf,
                                              const float* __restrict__ bf,
                                              float* __restrict__ out) {
    __shared__ __half h2s[64][264];       // 33.8 KB
    int lane = threadIdx.x & 63, hd = threadIdx.x >> 6;
    int quad = lane >> 4, l16 = lane & 15;
    // W_gat fragments for this wave's head
    half8 Bg[4][2];
#pragma unroll
    for (int nt = 0; nt < 4; nt++)
#pragma unroll
        for (int kc = 0; kc < 2; kc++) {
            const float* wp = Wg + (kc * 32 + quad * 8) * 256 + hd * 64 + nt * 16 + l16;
#pragma unroll
            for (int j = 0; j < 8; j++)
                Bg[nt][kc][j] = (_Float16)wp[j * 256];
        }
    float bbg[4];
#pragma unroll
    for (int nt = 0; nt < 4; nt++) bbg[nt] = bg[hd * 64 + nt * 16 + l16];
    // W_fc fragments (every wave)
    half8 Bf[2][8];
#pragma unroll
    for (int nt = 0; nt < 2; nt++)
#pragma unroll
        for (int kc = 0; kc < 8; kc++) {
            const float* wp = Wf + (kc * 32 + quad * 8) * 32 + nt * 16 + l16;
#pragma unroll
            for (int j = 0; j < 8; j++)
                Bf[nt][kc][j] = (_Float16)wp[j * 32];
        }
    float bb0 = bf[l16], bb1 = bf[16 + l16];

    int t0 = blockIdx.x * 4;
    // phase 1: h2 tile (64 rows x 256 cols) into LDS; wave hd owns 64 cols
#pragma unroll
    for (int i = 0; i < 4; i++) {
        int rt = t0 + i;
        if (rt >= NTILES) break;              // block-uniform
        const __half* up = u + ((size_t)(rt * 16 + l16)) * 256 + hd * 64 + quad * 8;
        half8 A0 = *(const half8*)(const void*)up;
        half8 A1 = *(const half8*)(const void*)(up + 32);
        f32x4 acc[4];
#pragma unroll
        for (int nt = 0; nt < 4; nt++) {
            acc[nt] = (f32x4){0.f, 0.f, 0.f, 0.f};
            acc[nt] = __builtin_amdgcn_mfma_f32_16x16x32_f16(A0, Bg[nt][0], acc[nt], 0, 0, 0);
            acc[nt] = __builtin_amdgcn_mfma_f32_16x16x32_f16(A1, Bg[nt][1], acc[nt], 0, 0, 0);
        }
#pragma unroll
        for (int nt = 0; nt < 4; nt++) {
            int col = hd * 64 + nt * 16 + l16;
#pragma unroll
            for (int reg = 0; reg < 4; reg++)
                h2s[i * 16 + quad * 4 + reg][col] = __float2half(fmaxf(acc[nt][reg] + bbg[nt], 0.f));
        }
    }
    __syncthreads();
    // phase 2: wave hd -> tile t0+hd
    int rt = t0 + hd;
    if (rt < NTILES) {
        f32x4 acc0 = {0.f, 0.f, 0.f, 0.f};
        f32x4 acc1 = {0.f, 0.f, 0.f, 0.f};
#pragma unroll
        for (int kc = 0; kc < 8; kc++) {
            half8 A = *(const half8*)(const void*)&h2s[hd * 16 + l16][kc * 32 + quad * 8];
            acc0 = __builtin_amdgcn_mfma_f32_16x16x32_f16(A, Bf[0][kc], acc0, 0, 0, 0);
            acc1 = __builtin_amdgcn_mfma_f32_16x16x32_f16(A, Bf[1][kc], acc1, 0, 0, 0);
        }
#pragma unroll
        for (int reg = 0; reg < 4; reg++) {
            int row = rt * 16 + quad * 4 + reg;
            out[row * 32 + l16]      = acc0[reg] + bb0;
            out[row * 32 + 16 + l16] = acc1[reg] + bb1;
        }
    }
}

// ---------------------------------------------------------------- launch
extern "C" void kernel_launch(void* const* d_in, const int* in_sizes, int n_in,
                              void* d_out, int out_size, void* d_ws, size_t ws_size,
                              hipStream_t stream) {
    const float* x      = (const float*)d_in[0];
    const int*   edge   = (const int*)  d_in[1];
    const float* W_gcn  = (const float*)d_in[2];
    const float* b_gcn  = (const float*)d_in[3];
    const float* W_gat  = (const float*)d_in[4];
    const float* att_s  = (const float*)d_in[5];
    const float* att_d  = (const float*)d_in[6];
    const float* b_gat  = (const float*)d_in[7];
    const float* W_fc   = (const float*)d_in[8];
    const float* b_fc   = (const float*)d_in[9];
    float* out = (float*)d_out;

    char* p = (char*)d_ws;
    auto alloc = [&](size_t bytes) {
        char* q = p;
        p += (bytes + 255) & ~(size_t)255;
        return q;
    };
    __half* h     = (__half*)alloc((size_t)(N_NODES + 1) * HID * 2);   // +1 zero row
    __half* h1    = (__half*)alloc((size_t)(N_NODES + 1) * HID * 2);   // +1 zero row
    __half* u     = (__half*)alloc((size_t)N_NODES * 256 * 2);
    float* as_a   = (float*)alloc((size_t)N_NODES * 4 * 4);
    float* ad_a   = (float*)alloc((size_t)N_NODES * 4 * 4);
    float* dinv   = (float*)alloc((size_t)N_NODES * 4);
    int*   rowptr = (int*)  alloc((size_t)(N_NODES + 1) * 4);
    unsigned short* colidx = (unsigned short*)alloc((size_t)N_EDGES * 2);
    int*   ghist  = (int*)  alloc((size_t)GH * 4);
    int*   bsum   = (int*)  alloc((size_t)NSB * 4);
    unsigned* tmp = (unsigned*)alloc((size_t)N_EDGES * 4);
    float* vsrc   = (float*)alloc((size_t)HEADS * HID * 4);
    float* vdst   = (float*)alloc((size_t)HEADS * HID * 4);

    // CSR build: atomic-free MSD bucket sort (hierarchical coalesced scan; attvec fused into scanB2)
    histA        <<<NBLK_A, 256, 0, stream>>>(edge, ghist);
    scanB1       <<<NSB, 256, 0, stream>>>(ghist, bsum);
    scanB2_attvec<<<2, 320, 0, stream>>>(bsum, W_gat, att_s, att_d, vsrc, vdst);
    scanB3       <<<NSB, 256, 0, stream>>>(ghist, bsum);
    scatterC     <<<NBLK_A, 512, 0, stream>>>(edge, ghist, tmp);
    sortD        <<<NBKT, 512, 0, stream>>>(tmp, ghist, colidx, rowptr, dinv);

    // GCN (gemm1 also zeroes the pad rows of h/h1)
    gemm1   <<<(N_NODES + 31) / 32, 256, 0, stream>>>(x, W_gcn, dinv, h, h1);
    gcn_agg <<<(N_NODES + 31) / 32, 256, 0, stream>>>(h, rowptr, colidx, dinv, b_gcn,
                                                      vsrc, vdst, h1, as_a, ad_a);

    // GAT
    gat_agg <<<(N_NODES + 31) / 32, 256, 0, stream>>>(h1, rowptr, colidx, as_a, ad_a, u);

    // fused GAT-linear + FC (h2 stays in LDS)
    gemm23  <<<(NTILES + 3) / 4, 256, 0, stream>>>(u, W_gat, b_gat, W_fc, b_fc, out);
}